// Round 1
// baseline (365.037 us; speedup 1.0000x reference)
//
#include <hip/hip_runtime.h>
#include <cstdint>
#include <cstddef>

#define N_ROWS 3456   // 16*216 chunks
#define C_DIM 256
#define K_CB 1024
#define B_SZ 16
#define SPATIAL 216
#define VOX 13824     // 24*24*24
#define NCH 32

// ---------------------------------------------------------------- K0: init
__global__ void k_init(float* __restrict__ avgp, float* __restrict__ scal) {
    int t = blockIdx.x * blockDim.x + threadIdx.x;
    if (t < K_CB) avgp[t] = 0.0f;
    if (t < 8) scal[t] = 0.0f;
}

// ------------------------------------------------------------ K1: patterns
// binary[v] = (argmax_c input[b,c,voxel] != 0) = (max_{c>=1} > val0)
// pattern[n] = 64 consecutive voxels' bits (plain-reshape equivalence)
__global__ void k_patterns(const float* __restrict__ in,
                           unsigned long long* __restrict__ pats) {
    int v = blockIdx.x * 256 + threadIdx.x;       // 0..221183
    int b = v / VOX;
    int r = v % VOX;
    const float* p = in + (size_t)b * NCH * VOX + r;
    float v0 = p[0];
    float mx = -INFINITY;
#pragma unroll
    for (int c = 1; c < NCH; ++c) mx = fmaxf(mx, p[(size_t)c * VOX]);
    bool bit = mx > v0;
    unsigned long long m = __ballot(bit);
    if ((threadIdx.x & 63) == 0) pats[v >> 6] = m;
}

// ------------------------------------------------- K2: normalize codebook
__global__ void k_norm_cb(const float* __restrict__ cb,
                          float* __restrict__ en, float* __restrict__ enT) {
    int k = blockIdx.x, c = threadIdx.x;
    float v = cb[k * C_DIM + c];
    float ss = v * v;
#pragma unroll
    for (int off = 32; off > 0; off >>= 1) ss += __shfl_down(ss, off, 64);
    __shared__ float ws[4];
    if ((c & 63) == 0) ws[c >> 6] = ss;
    __syncthreads();
    float tot = ws[0] + ws[1] + ws[2] + ws[3];
    float nrm = fmaxf(sqrtf(tot), 1e-12f);
    float o = v / nrm;
    en[k * C_DIM + c] = o;
    enT[c * K_CB + k] = o;
}

// ------------------------------------------------------ K3: normalize z_e
__global__ void k_norm_z(const float* __restrict__ ze, float* __restrict__ zn) {
    int n = blockIdx.x, c = threadIdx.x;
    int b = n / SPATIAL, s = n % SPATIAL;
    float v = ze[((size_t)(b * C_DIM + c)) * SPATIAL + s];
    float ss = v * v;
#pragma unroll
    for (int off = 32; off > 0; off >>= 1) ss += __shfl_down(ss, off, 64);
    __shared__ float ws[4];
    if ((c & 63) == 0) ws[c >> 6] = ss;
    __syncthreads();
    float tot = ws[0] + ws[1] + ws[2] + ws[3];
    float nrm = fmaxf(sqrtf(tot), 1e-12f);
    zn[n * C_DIM + c] = v / nrm;
}

// -------------------- K4: affinity + argmax + softmax stats (8 rows/block)
// thread t owns k = 4t..4t+3 for all 8 rows; enT gives coalesced loads.
__global__ __launch_bounds__(256) void k_affinity(
        const float* __restrict__ zn, const float* __restrict__ enT,
        float* __restrict__ avgp, float* __restrict__ scal,
        int* __restrict__ idx_arr, float* __restrict__ out_idx) {
    __shared__ float zs[8 * C_DIM];
    __shared__ float rv[256 * 8];
    __shared__ int   ri[256 * 8];
    __shared__ float m8[8], s8[8], t8[8];
    __shared__ int   i8[8];
    int t = threadIdx.x;
    int n0 = blockIdx.x * 8;
    for (int i = t; i < 8 * C_DIM; i += 256) zs[i] = zn[n0 * C_DIM + i];
    __syncthreads();

    float acc[4][8];
#pragma unroll
    for (int i = 0; i < 4; ++i)
#pragma unroll
        for (int n = 0; n < 8; ++n) acc[i][n] = 0.0f;
    int k0 = t * 4;

    for (int c4 = 0; c4 < 64; ++c4) {
        float4 z[8];
#pragma unroll
        for (int n = 0; n < 8; ++n)
            z[n] = *(const float4*)&zs[n * C_DIM + c4 * 4];
#pragma unroll
        for (int cc = 0; cc < 4; ++cc) {
            float4 e = *(const float4*)&enT[(size_t)(c4 * 4 + cc) * K_CB + k0];
#pragma unroll
            for (int n = 0; n < 8; ++n) {
                float zc = ((const float*)&z[n])[cc];
                acc[0][n] += e.x * zc;
                acc[1][n] += e.y * zc;
                acc[2][n] += e.z * zc;
                acc[3][n] += e.w * zc;
            }
        }
    }

    // local argmax per row
    float lm[8]; int li[8];
#pragma unroll
    for (int n = 0; n < 8; ++n) {
        lm[n] = acc[0][n]; li[n] = k0;
#pragma unroll
        for (int i = 1; i < 4; ++i)
            if (acc[i][n] > lm[n]) { lm[n] = acc[i][n]; li[n] = k0 + i; }
    }
#pragma unroll
    for (int n = 0; n < 8; ++n) { rv[t * 8 + n] = lm[n]; ri[t * 8 + n] = li[n]; }
    __syncthreads();
    for (int s = 128; s > 0; s >>= 1) {
        if (t < s) {
#pragma unroll
            for (int n = 0; n < 8; ++n) {
                float v2 = rv[(t + s) * 8 + n]; int j2 = ri[(t + s) * 8 + n];
                float v1 = rv[t * 8 + n];       int j1 = ri[t * 8 + n];
                if (v2 > v1 || (v2 == v1 && j2 < j1)) {
                    rv[t * 8 + n] = v2; ri[t * 8 + n] = j2;
                }
            }
        }
        __syncthreads();
    }
    if (t < 8) { m8[t] = rv[t]; i8[t] = ri[t]; }
    __syncthreads();

    // S = sum exp(100*(aff - m))
    float ls[8];
#pragma unroll
    for (int n = 0; n < 8; ++n) {
        float s = 0.0f;
#pragma unroll
        for (int i = 0; i < 4; ++i) s += __expf(100.0f * (acc[i][n] - m8[n]));
        ls[n] = s;
    }
#pragma unroll
    for (int n = 0; n < 8; ++n) rv[t * 8 + n] = ls[n];
    __syncthreads();
    for (int s = 128; s > 0; s >>= 1) {
        if (t < s)
#pragma unroll
            for (int n = 0; n < 8; ++n) rv[t * 8 + n] += rv[(t + s) * 8 + n];
        __syncthreads();
    }
    if (t < 8) s8[t] = rv[t];
    __syncthreads();

    // T = sum e*d ; avg_probs accumulation (p summed over the 8 rows)
    float lt[8];
    float ps[4] = {0.0f, 0.0f, 0.0f, 0.0f};
#pragma unroll
    for (int n = 0; n < 8; ++n) {
        float tn = 0.0f;
        float inv_s = 1.0f / s8[n];
#pragma unroll
        for (int i = 0; i < 4; ++i) {
            float d = 100.0f * (acc[i][n] - m8[n]);
            float e = __expf(d);
            tn += e * d;
            ps[i] += e * inv_s;
        }
        lt[n] = tn;
    }
#pragma unroll
    for (int i = 0; i < 4; ++i) atomicAdd(&avgp[k0 + i], ps[i]);
#pragma unroll
    for (int n = 0; n < 8; ++n) rv[t * 8 + n] = lt[n];
    __syncthreads();
    for (int s = 128; s > 0; s >>= 1) {
        if (t < s)
#pragma unroll
            for (int n = 0; n < 8; ++n) rv[t * 8 + n] += rv[(t + s) * 8 + n];
        __syncthreads();
    }
    if (t < 8) t8[t] = rv[t];
    __syncthreads();

    if (t == 0) {
        float se = 0.0f, cm = 0.0f;
#pragma unroll
        for (int n = 0; n < 8; ++n) {
            se += logf(s8[n]) - t8[n] / s8[n];  // -sum p log p
            cm += 2.0f - 2.0f * m8[n];          // ||en[idx]-zn||^2
        }
        atomicAdd(&scal[0], se);
        atomicAdd(&scal[1], cm);
    }
    if (t < 8) {
        idx_arr[n0 + t] = i8[t];
        out_idx[n0 + t] = (float)i8[t];
    }
}

// --------------------------- K5: pairwise hamming-weighted cosine distance
// 128(i) x 64(j) tile per block, 8x4 micro-tile/thread, c staged in 4 chunks.
// rows in micro-tile spaced 16 apart -> LDS bank spread with stride 68.
#define ZI_STRIDE 68
__global__ __launch_bounds__(256) void k_ham(
        const float* __restrict__ zn,
        const unsigned long long* __restrict__ pats,
        float* __restrict__ scal) {
    __shared__ float zi[128 * ZI_STRIDE];
    __shared__ float zj[64 * ZI_STRIDE];
    int t = threadIdx.x;
    int i0 = blockIdx.x * 128, j0 = blockIdx.y * 64;
    int im = t & 15, jq = t >> 4;

    float acc[8][4];
#pragma unroll
    for (int r = 0; r < 8; ++r)
#pragma unroll
        for (int q = 0; q < 4; ++q) acc[r][q] = 0.0f;

    for (int ck = 0; ck < 4; ++ck) {
        __syncthreads();
        // stage zi: 128 rows x 64 cols (float4 granularity)
#pragma unroll
        for (int l = 0; l < 8; ++l) {
            int fl4 = l * 256 + t;
            int row = fl4 >> 4, col4 = fl4 & 15;
            *(float4*)&zi[row * ZI_STRIDE + col4 * 4] =
                *(const float4*)&zn[(size_t)(i0 + row) * C_DIM + ck * 64 + col4 * 4];
        }
        // stage zj: 64 rows x 64 cols
#pragma unroll
        for (int l = 0; l < 4; ++l) {
            int fl4 = l * 256 + t;
            int row = fl4 >> 4, col4 = fl4 & 15;
            *(float4*)&zj[row * ZI_STRIDE + col4 * 4] =
                *(const float4*)&zn[(size_t)(j0 + row) * C_DIM + ck * 64 + col4 * 4];
        }
        __syncthreads();

        for (int c4 = 0; c4 < 16; ++c4) {
            float4 a[8], b4[4];
#pragma unroll
            for (int r = 0; r < 8; ++r)
                a[r] = *(const float4*)&zi[(im + 16 * r) * ZI_STRIDE + c4 * 4];
#pragma unroll
            for (int q = 0; q < 4; ++q)
                b4[q] = *(const float4*)&zj[(jq + 16 * q) * ZI_STRIDE + c4 * 4];
#pragma unroll
            for (int r = 0; r < 8; ++r)
#pragma unroll
                for (int q = 0; q < 4; ++q)
                    acc[r][q] += a[r].x * b4[q].x + a[r].y * b4[q].y +
                                 a[r].z * b4[q].z + a[r].w * b4[q].w;
        }
    }

    // mask by hamming similarity, accumulate sum(W) and sum(dist*W)
    unsigned long long pi[8], pj[4];
#pragma unroll
    for (int r = 0; r < 8; ++r) pi[r] = pats[i0 + im + 16 * r];
#pragma unroll
    for (int q = 0; q < 4; ++q) pj[q] = pats[j0 + jq + 16 * q];

    float sW = 0.0f, sDW = 0.0f;
#pragma unroll
    for (int r = 0; r < 8; ++r) {
        int gi = i0 + im + 16 * r;
#pragma unroll
        for (int q = 0; q < 4; ++q) {
            int gj = j0 + jq + 16 * q;
            int pop = __popcll(pi[r] ^ pj[q]);
            // sim > 0.92  <=>  pop <= 5 (exact in fp32)
            float w = (pop <= 5 && gi != gj) ? (1.0f - (float)pop * 0.015625f) : 0.0f;
            sW += w;
            sDW += (1.0f - acc[r][q]) * w;
        }
    }
#pragma unroll
    for (int off = 32; off > 0; off >>= 1) {
        sW += __shfl_down(sW, off, 64);
        sDW += __shfl_down(sDW, off, 64);
    }
    if ((t & 63) == 0) {
        atomicAdd(&scal[2], sW);
        atomicAdd(&scal[3], sDW);
    }
}

// --------------------------------------------------- K6: z_q output gather
__global__ void k_zq(const float* __restrict__ en, const int* __restrict__ idx,
                     float* __restrict__ out) {
    int blk = blockIdx.x;           // b*256 + c
    int b = blk >> 8, c = blk & 255;
    int s = threadIdx.x;
    if (s < SPATIAL) {
        int n = b * SPATIAL + s;
        out[(size_t)blk * SPATIAL + s] = en[(size_t)idx[n] * C_DIM + c];
    }
}

// ------------------------------------------------- K7: final loss combine
__global__ void k_final(const float* __restrict__ avgp,
                        const float* __restrict__ scal,
                        float* __restrict__ out_loss) {
    int t = threadIdx.x;   // 1024 threads
    float ap = avgp[t] * (1.0f / N_ROWS);
    float term = ap * logf(ap + 1e-5f);   // avg_entropy = -sum(term)
#pragma unroll
    for (int off = 32; off > 0; off >>= 1) term += __shfl_down(term, off, 64);
    __shared__ float ws[16];
    if ((t & 63) == 0) ws[t >> 6] = term;
    __syncthreads();
    if (t == 0) {
        float sAP = 0.0f;
#pragma unroll
        for (int i = 0; i < 16; ++i) sAP += ws[i];
        float sample = scal[0] * (1.0f / N_ROWS);
        float commit = scal[1] * (1.0f / ((float)N_ROWS * C_DIM));
        float ent = 0.1f * (sample + sAP);      // sample_entropy - avg_entropy
        float ham = scal[3] / (scal[2] + 1e-8f);
        *out_loss = 1.25f * commit + ent + ham;
    }
}

// ----------------------------------------------------------------- launch
extern "C" void kernel_launch(void* const* d_in, const int* in_sizes, int n_in,
                              void* d_out, int out_size, void* d_ws, size_t ws_size,
                              hipStream_t stream) {
    const float* in_blocks = (const float*)d_in[0];  // [16,32,24,24,24]
    const float* z_e       = (const float*)d_in[1];  // [16,256,6,6,6]
    const float* cb        = (const float*)d_in[2];  // [1024,256]
    float* out = (float*)d_out;  // [884736 z_q][1 loss][3456 idx]

    char* ws = (char*)d_ws;
    float* zn   = (float*)(ws + 0);            // 3,538,944 B
    float* en   = (float*)(ws + 3538944);      // 1,048,576 B
    float* enT  = (float*)(ws + 4587520);      // 1,048,576 B
    unsigned long long* pats = (unsigned long long*)(ws + 5636096); // 27,648 B
    int*   idx  = (int*)(ws + 5663744);        // 13,824 B
    float* avgp = (float*)(ws + 5677568);      // 4,096 B
    float* scal = (float*)(ws + 5681664);      // 32 B

    k_init<<<4, 256, 0, stream>>>(avgp, scal);
    k_patterns<<<864, 256, 0, stream>>>(in_blocks, pats);
    k_norm_cb<<<1024, 256, 0, stream>>>(cb, en, enT);
    k_norm_z<<<3456, 256, 0, stream>>>(z_e, zn);
    k_affinity<<<432, 256, 0, stream>>>(zn, enT, avgp, scal, idx, out + 884737);
    k_ham<<<dim3(27, 54), 256, 0, stream>>>(zn, pats, scal);
    k_zq<<<4096, 256, 0, stream>>>(en, idx, out);
    k_final<<<1, 1024, 0, stream>>>(avgp, scal, out + 884736);
}

// Round 2
// 209.778 us; speedup vs baseline: 1.7401x; 1.7401x over previous
//
#include <hip/hip_runtime.h>
#include <cstdint>
#include <cstddef>

#define N_ROWS 3456   // 16*216 chunks
#define C_DIM 256
#define K_CB 1024
#define B_SZ 16
#define SPATIAL 216
#define VOX 13824     // 24*24*24
#define NCH 32

typedef __attribute__((ext_vector_type(16))) float f32x16;
typedef __attribute__((ext_vector_type(8))) short bf16x8;

// ---------------------------------------------------------------- K0: init
__global__ void k_init(float* __restrict__ avgp, float* __restrict__ scal) {
    int t = blockIdx.x * blockDim.x + threadIdx.x;
    if (t < K_CB) avgp[t] = 0.0f;
    if (t < 8) scal[t] = 0.0f;
}

// ------------------------------------------------------------ K1: patterns
__global__ void k_patterns(const float* __restrict__ in,
                           unsigned long long* __restrict__ pats) {
    int v = blockIdx.x * 256 + threadIdx.x;       // 0..221183
    int b = v / VOX;
    int r = v % VOX;
    const float* p = in + (size_t)b * NCH * VOX + r;
    float v0 = p[0];
    float mx = -INFINITY;
#pragma unroll
    for (int c = 1; c < NCH; ++c) mx = fmaxf(mx, p[(size_t)c * VOX]);
    bool bit = mx > v0;
    unsigned long long m = __ballot(bit);
    if ((threadIdx.x & 63) == 0) pats[v >> 6] = m;
}

// ------------------------------------------------- K2: normalize codebook
__global__ void k_norm_cb(const float* __restrict__ cb,
                          float* __restrict__ en, float* __restrict__ enT) {
    int k = blockIdx.x, c = threadIdx.x;
    float v = cb[k * C_DIM + c];
    float ss = v * v;
#pragma unroll
    for (int off = 32; off > 0; off >>= 1) ss += __shfl_down(ss, off, 64);
    __shared__ float ws[4];
    if ((c & 63) == 0) ws[c >> 6] = ss;
    __syncthreads();
    float tot = ws[0] + ws[1] + ws[2] + ws[3];
    float nrm = fmaxf(sqrtf(tot), 1e-12f);
    float o = v / nrm;
    en[k * C_DIM + c] = o;
    enT[c * K_CB + k] = o;
}

// ------------------------------ K3: normalize z_e (fp32 + bf16 copies)
__device__ __forceinline__ unsigned short f2bf_rne(float f) {
    unsigned int u = __float_as_uint(f);
    u += 0x7FFFu + ((u >> 16) & 1u);
    return (unsigned short)(u >> 16);
}
__global__ void k_norm_z(const float* __restrict__ ze, float* __restrict__ zn,
                         unsigned short* __restrict__ znb) {
    int n = blockIdx.x, c = threadIdx.x;
    int b = n / SPATIAL, s = n % SPATIAL;
    float v = ze[((size_t)(b * C_DIM + c)) * SPATIAL + s];
    float ss = v * v;
#pragma unroll
    for (int off = 32; off > 0; off >>= 1) ss += __shfl_down(ss, off, 64);
    __shared__ float ws[4];
    if ((c & 63) == 0) ws[c >> 6] = ss;
    __syncthreads();
    float tot = ws[0] + ws[1] + ws[2] + ws[3];
    float nrm = fmaxf(sqrtf(tot), 1e-12f);
    float o = v / nrm;
    zn[n * C_DIM + c] = o;
    znb[n * C_DIM + c] = f2bf_rne(o);
}

// -------------------- K4: affinity + argmax + softmax stats (8 rows/block)
__global__ __launch_bounds__(256) void k_affinity(
        const float* __restrict__ zn, const float* __restrict__ enT,
        float* __restrict__ avgp, float* __restrict__ scal,
        int* __restrict__ idx_arr, float* __restrict__ out_idx) {
    __shared__ float zs[8 * C_DIM];
    __shared__ float rv[256 * 8];
    __shared__ int   ri[256 * 8];
    __shared__ float m8[8], s8[8], t8[8];
    __shared__ int   i8[8];
    int t = threadIdx.x;
    int n0 = blockIdx.x * 8;
    for (int i = t; i < 8 * C_DIM; i += 256) zs[i] = zn[n0 * C_DIM + i];
    __syncthreads();

    float acc[4][8];
#pragma unroll
    for (int i = 0; i < 4; ++i)
#pragma unroll
        for (int n = 0; n < 8; ++n) acc[i][n] = 0.0f;
    int k0 = t * 4;

    for (int c4 = 0; c4 < 64; ++c4) {
        float4 z[8];
#pragma unroll
        for (int n = 0; n < 8; ++n)
            z[n] = *(const float4*)&zs[n * C_DIM + c4 * 4];
#pragma unroll
        for (int cc = 0; cc < 4; ++cc) {
            float4 e = *(const float4*)&enT[(size_t)(c4 * 4 + cc) * K_CB + k0];
#pragma unroll
            for (int n = 0; n < 8; ++n) {
                float zc = ((const float*)&z[n])[cc];
                acc[0][n] += e.x * zc;
                acc[1][n] += e.y * zc;
                acc[2][n] += e.z * zc;
                acc[3][n] += e.w * zc;
            }
        }
    }

    float lm[8]; int li[8];
#pragma unroll
    for (int n = 0; n < 8; ++n) {
        lm[n] = acc[0][n]; li[n] = k0;
#pragma unroll
        for (int i = 1; i < 4; ++i)
            if (acc[i][n] > lm[n]) { lm[n] = acc[i][n]; li[n] = k0 + i; }
    }
#pragma unroll
    for (int n = 0; n < 8; ++n) { rv[t * 8 + n] = lm[n]; ri[t * 8 + n] = li[n]; }
    __syncthreads();
    for (int s = 128; s > 0; s >>= 1) {
        if (t < s) {
#pragma unroll
            for (int n = 0; n < 8; ++n) {
                float v2 = rv[(t + s) * 8 + n]; int j2 = ri[(t + s) * 8 + n];
                float v1 = rv[t * 8 + n];       int j1 = ri[t * 8 + n];
                if (v2 > v1 || (v2 == v1 && j2 < j1)) {
                    rv[t * 8 + n] = v2; ri[t * 8 + n] = j2;
                }
            }
        }
        __syncthreads();
    }
    if (t < 8) { m8[t] = rv[t]; i8[t] = ri[t]; }
    __syncthreads();

    float ls[8];
#pragma unroll
    for (int n = 0; n < 8; ++n) {
        float s = 0.0f;
#pragma unroll
        for (int i = 0; i < 4; ++i) s += __expf(100.0f * (acc[i][n] - m8[n]));
        ls[n] = s;
    }
#pragma unroll
    for (int n = 0; n < 8; ++n) rv[t * 8 + n] = ls[n];
    __syncthreads();
    for (int s = 128; s > 0; s >>= 1) {
        if (t < s)
#pragma unroll
            for (int n = 0; n < 8; ++n) rv[t * 8 + n] += rv[(t + s) * 8 + n];
        __syncthreads();
    }
    if (t < 8) s8[t] = rv[t];
    __syncthreads();

    float lt[8];
    float ps[4] = {0.0f, 0.0f, 0.0f, 0.0f};
#pragma unroll
    for (int n = 0; n < 8; ++n) {
        float tn = 0.0f;
        float inv_s = 1.0f / s8[n];
#pragma unroll
        for (int i = 0; i < 4; ++i) {
            float d = 100.0f * (acc[i][n] - m8[n]);
            float e = __expf(d);
            tn += e * d;
            ps[i] += e * inv_s;
        }
        lt[n] = tn;
    }
#pragma unroll
    for (int i = 0; i < 4; ++i) atomicAdd(&avgp[k0 + i], ps[i]);
#pragma unroll
    for (int n = 0; n < 8; ++n) rv[t * 8 + n] = lt[n];
    __syncthreads();
    for (int s = 128; s > 0; s >>= 1) {
        if (t < s)
#pragma unroll
            for (int n = 0; n < 8; ++n) rv[t * 8 + n] += rv[(t + s) * 8 + n];
        __syncthreads();
    }
    if (t < 8) t8[t] = rv[t];
    __syncthreads();

    if (t == 0) {
        float se = 0.0f, cm = 0.0f;
#pragma unroll
        for (int n = 0; n < 8; ++n) {
            se += logf(s8[n]) - t8[n] / s8[n];
            cm += 2.0f - 2.0f * m8[n];
        }
        atomicAdd(&scal[0], se);
        atomicAdd(&scal[1], cm);
    }
    if (t < 8) {
        idx_arr[n0 + t] = i8[t];
        out_idx[n0 + t] = (float)i8[t];
    }
}

// ---------------- K5: pairwise Gram via bf16 MFMA, upper-triangular tiles
// scal[2] += factor * sum(W); scal[3] += factor * sum(W * cos)
#define HSTR 72   // bf16 row stride: 64 data + 8 pad (144 B == 4 mod 32 banks)
__global__ __launch_bounds__(128) void k_ham(
        const unsigned short* __restrict__ znb,
        const unsigned long long* __restrict__ pats,
        float* __restrict__ scal) {
    // decode upper-tri tile pair (ti <= tj), 27x27 tiles of 128 rows
    int bid = blockIdx.x;            // 0..377
    int ti = 0, rem = bid;
    while (rem >= 27 - ti) { rem -= 27 - ti; ++ti; }
    int tj = ti + rem;
    int i0 = ti * 128, j0 = tj * 128;
    float factor = (ti == tj) ? 1.0f : 2.0f;

    __shared__ __align__(16) unsigned short zi[128 * HSTR];
    __shared__ __align__(16) unsigned short zj[128 * HSTR];

    int t = threadIdx.x;       // 0..127
    int w = t >> 6;            // wave 0..1 (i-strip)
    int lane = t & 63;

    f32x16 acc[2][4];
#pragma unroll
    for (int a = 0; a < 2; ++a)
#pragma unroll
        for (int b = 0; b < 4; ++b)
#pragma unroll
            for (int e = 0; e < 16; ++e) acc[a][b][e] = 0.0f;

    for (int ck = 0; ck < 4; ++ck) {     // K chunks of 64
        __syncthreads();
#pragma unroll
        for (int p = 0; p < 8; ++p) {    // stage 128 rows x 64 bf16 each buf
            int row = p * 16 + (t >> 3);
            int seg = t & 7;             // 16B segment
            *(float4*)&zi[row * HSTR + seg * 8] =
                *(const float4*)&znb[(size_t)(i0 + row) * C_DIM + ck * 64 + seg * 8];
            *(float4*)&zj[row * HSTR + seg * 8] =
                *(const float4*)&znb[(size_t)(j0 + row) * C_DIM + ck * 64 + seg * 8];
        }
        __syncthreads();

#pragma unroll
        for (int ks = 0; ks < 4; ++ks) { // 4 MFMA k-steps of 16
            int off = (lane & 31) * HSTR + (lane >> 5) * 8 + ks * 16;
            bf16x8 a0 = *(bf16x8*)&zi[(w * 64) * HSTR + off];
            bf16x8 a1 = *(bf16x8*)&zi[(w * 64 + 32) * HSTR + off];
            bf16x8 bf[4];
#pragma unroll
            for (int c = 0; c < 4; ++c)
                bf[c] = *(bf16x8*)&zj[(c * 32) * HSTR + off];
#pragma unroll
            for (int c = 0; c < 4; ++c) {
                acc[0][c] = __builtin_amdgcn_mfma_f32_32x32x16_bf16(a0, bf[c], acc[0][c], 0, 0, 0);
                acc[1][c] = __builtin_amdgcn_mfma_f32_32x32x16_bf16(a1, bf[c], acc[1][c], 0, 0, 0);
            }
        }
    }

    // epilogue: weight by hamming mask, accumulate
    unsigned long long pj[4];
#pragma unroll
    for (int c = 0; c < 4; ++c) pj[c] = pats[j0 + c * 32 + (lane & 31)];

    float sW = 0.0f, sD = 0.0f;
#pragma unroll
    for (int r = 0; r < 2; ++r) {
        int ibase = i0 + w * 64 + r * 32 + 4 * (lane >> 5);
#pragma unroll
        for (int g = 0; g < 16; ++g) {
            int gi = ibase + (g & 3) + 8 * (g >> 2);
            unsigned long long pi = pats[gi];
#pragma unroll
            for (int c = 0; c < 4; ++c) {
                int gj = j0 + c * 32 + (lane & 31);
                int pop = __popcll(pi ^ pj[c]);
                float wgt = (pop <= 5 && gi != gj) ? (1.0f - (float)pop * 0.015625f) : 0.0f;
                sW += wgt;
                sD += wgt * acc[r][c][g];
            }
        }
    }
#pragma unroll
    for (int off = 32; off > 0; off >>= 1) {
        sW += __shfl_down(sW, off, 64);
        sD += __shfl_down(sD, off, 64);
    }
    if (lane == 0) {
        atomicAdd(&scal[2], factor * sW);
        atomicAdd(&scal[3], factor * sD);
    }
}

// --------------------------------------------------- K6: z_q output gather
__global__ void k_zq(const float* __restrict__ en, const int* __restrict__ idx,
                     float* __restrict__ out) {
    int blk = blockIdx.x;           // b*256 + c
    int b = blk >> 8, c = blk & 255;
    int s = threadIdx.x;
    if (s < SPATIAL) {
        int n = b * SPATIAL + s;
        out[(size_t)blk * SPATIAL + s] = en[(size_t)idx[n] * C_DIM + c];
    }
}

// ------------------------------------------------- K7: final loss combine
__global__ void k_final(const float* __restrict__ avgp,
                        const float* __restrict__ scal,
                        float* __restrict__ out_loss) {
    int t = threadIdx.x;   // 1024 threads
    float ap = avgp[t] * (1.0f / N_ROWS);
    float term = ap * logf(ap + 1e-5f);
#pragma unroll
    for (int off = 32; off > 0; off >>= 1) term += __shfl_down(term, off, 64);
    __shared__ float ws[16];
    if ((t & 63) == 0) ws[t >> 6] = term;
    __syncthreads();
    if (t == 0) {
        float sAP = 0.0f;
#pragma unroll
        for (int i = 0; i < 16; ++i) sAP += ws[i];
        float sample = scal[0] * (1.0f / N_ROWS);
        float commit = scal[1] * (1.0f / ((float)N_ROWS * C_DIM));
        float ent = 0.1f * (sample + sAP);
        float ham = (scal[2] - scal[3]) / (scal[2] + 1e-8f);  // sum(dist*W)/sum(W)
        *out_loss = 1.25f * commit + ent + ham;
    }
}

// ----------------------------------------------------------------- launch
extern "C" void kernel_launch(void* const* d_in, const int* in_sizes, int n_in,
                              void* d_out, int out_size, void* d_ws, size_t ws_size,
                              hipStream_t stream) {
    const float* in_blocks = (const float*)d_in[0];  // [16,32,24,24,24]
    const float* z_e       = (const float*)d_in[1];  // [16,256,6,6,6]
    const float* cb        = (const float*)d_in[2];  // [1024,256]
    float* out = (float*)d_out;  // [884736 z_q][1 loss][3456 idx]

    char* ws = (char*)d_ws;
    float* zn   = (float*)(ws + 0);            // 3,538,944 B
    float* en   = (float*)(ws + 3538944);      // 1,048,576 B
    float* enT  = (float*)(ws + 4587520);      // 1,048,576 B
    unsigned long long* pats = (unsigned long long*)(ws + 5636096); // 27,648 B
    int*   idx  = (int*)(ws + 5663744);        // 13,824 B
    float* avgp = (float*)(ws + 5677568);      // 4,096 B
    float* scal = (float*)(ws + 5681664);      // 64 B
    unsigned short* znb = (unsigned short*)(ws + 5681728); // 1,769,472 B -> 7,451,200 total

    k_init<<<4, 256, 0, stream>>>(avgp, scal);
    k_patterns<<<864, 256, 0, stream>>>(in_blocks, pats);
    k_norm_cb<<<1024, 256, 0, stream>>>(cb, en, enT);
    k_norm_z<<<3456, 256, 0, stream>>>(z_e, zn, znb);
    k_affinity<<<432, 256, 0, stream>>>(zn, enT, avgp, scal, idx, out + 884737);
    k_ham<<<378, 128, 0, stream>>>(znb, pats, scal);
    k_zq<<<4096, 256, 0, stream>>>(en, idx, out);
    k_final<<<1, 1024, 0, stream>>>(avgp, scal, out + 884736);
}